// Round 2
// baseline (861.427 us; speedup 1.0000x reference)
//
#include <hip/hip_runtime.h>

// Problem constants (from reference)
#define NVOX 150000
#define NPAD 150016          // 1172 * 128 row tiles
#define CCH  256
#define ZROW NVOX            // zero row for -1 neighbors (pad rows zeroed)
#define BM   128

typedef __attribute__((ext_vector_type(8))) short bfrag_t;   // 8 bf16 = 4 VGPRs
typedef __attribute__((ext_vector_type(4))) float accfrag_t; // 4 fp32

__device__ __forceinline__ void async_copy16(const void* g, void* l) {
  __builtin_amdgcn_global_load_lds(
      (const __attribute__((address_space(1))) void*)g,
      (__attribute__((address_space(3))) void*)l, 16, 0, 0);
}

__device__ __forceinline__ unsigned short f2bf(float x) {
  unsigned int u = __float_as_uint(x);
  unsigned int r = (u + 0x7FFFu + ((u >> 16) & 1u)) >> 16;  // RNE
  return (unsigned short)r;
}

// ---- feats fp32 -> bf16 (padded, pad rows zeroed) ----
__global__ __launch_bounds__(256) void cvt_feats_kernel(
    const float* __restrict__ f, unsigned short* __restrict__ o) {
  int t = blockIdx.x * 256 + threadIdx.x;        // 8 elements per thread
  int row = t >> 5;                              // 32 threads per 256-ch row
  bfrag_t pack;
  if (row < NVOX) {
    const float4* fp = (const float4*)f;
    float4 a = fp[2 * t];
    float4 b = fp[2 * t + 1];
    float v[8] = {a.x, a.y, a.z, a.w, b.x, b.y, b.z, b.w};
#pragma unroll
    for (int i = 0; i < 8; ++i) pack[i] = (short)f2bf(v[i]);
  } else {
#pragma unroll
    for (int i = 0; i < 8; ++i) pack[i] = 0;
  }
  *(bfrag_t*)(o + (size_t)t * 8) = pack;
}

// ---- weights fp32 [3][cin][cout] -> bf16 transposed Wt[9][cout][cin] ----
// LDS-tiled transpose: coalesced reads AND writes.
__global__ __launch_bounds__(256) void cvt_w_kernel(
    const float* __restrict__ w1, const float* __restrict__ w2,
    const float* __restrict__ w3, unsigned short* __restrict__ o) {
  __shared__ float tile[32][33];
  int g9 = blockIdx.z;                       // conv*3+tap
  int k0 = blockIdx.x * 32, n0 = blockIdx.y * 32;
  int tx = threadIdx.x & 31, ty = threadIdx.x >> 5;  // 32 x 8
  const float* w = (g9 < 3) ? w1 : ((g9 < 6) ? w2 : w3);
  int tap = (g9 < 3) ? g9 : ((g9 < 6) ? g9 - 3 : g9 - 6);
#pragma unroll
  for (int i = 0; i < 4; ++i) {
    int k = k0 + ty + i * 8;
    tile[ty + i * 8][tx] = w[((size_t)(tap * 256 + k)) * 256 + n0 + tx];
  }
  __syncthreads();
#pragma unroll
  for (int i = 0; i < 4; ++i) {
    int n = n0 + ty + i * 8;
    o[((size_t)g9 << 16) + (size_t)n * 256 + k0 + tx] = f2bf(tile[tx][ty + i * 8]);
  }
}

// ---- staging helpers for the fused kernel ----
// LDS half-K buffer: 128 rows x 16 chunks of 16B (row stride 256B), chunk
// XOR-swizzled: phys = logical ^ (row & 15)  -> conflict-free ds_read_b128.

__device__ __forceinline__ void load_nb(const int* __restrict__ nbr, int tap,
                                        int m0, int wid, int lane, int nb[4]) {
#pragma unroll
  for (int iss = 0; iss < 4; ++iss) {
    int lrow = iss * 32 + wid * 4 + (lane >> 4);
    int gr = m0 + lrow;
    int grc = (gr < NVOX) ? gr : (NVOX - 1);
    int nbi = nbr[grc * 3 + tap];
    nb[iss] = (gr < NVOX && nbi >= 0) ? nbi : ZROW;
  }
}

__device__ __forceinline__ void issue_stage(const unsigned short* __restrict__ F16,
                                            unsigned short* buf, int half,
                                            const int nb[4], int wid, int lane) {
  int cphys = lane & 15;
#pragma unroll
  for (int iss = 0; iss < 4; ++iss) {
    int lrow = iss * 32 + wid * 4 + (lane >> 4);
    int c = cphys ^ (lrow & 15);               // source-side swizzle
    const unsigned short* src =
        F16 + ((size_t)nb[iss] << 8) + half * 128 + (c << 3);
    char* dst = (char*)buf + (size_t)(iss * 32 + wid * 4) * 256;  // wave-uniform
    async_copy16(src, dst);
  }
}

__device__ __forceinline__ void compute_half(const unsigned short* buf,
                                             const unsigned short* __restrict__ Wtap,
                                             int half, int wm, int m, int quad,
                                             int col_base, accfrag_t acc[4][2]) {
#pragma unroll
  for (int ks = 0; ks < 4; ++ks) {
    bfrag_t a[4], bb[2];
#pragma unroll
    for (int mt = 0; mt < 4; ++mt) {
      int row = wm * 64 + mt * 16 + m;
      int phys = (ks * 4 + quad) ^ (row & 15);
      a[mt] = *(const bfrag_t*)((const char*)buf + row * 256 + phys * 16);
    }
#pragma unroll
    for (int nt = 0; nt < 2; ++nt) {
      int col = col_base + nt * 16 + m;
      bb[nt] = *(const bfrag_t*)(Wtap + (size_t)col * 256 + half * 128 + ks * 32 + quad * 8);
    }
#pragma unroll
    for (int mt = 0; mt < 4; ++mt)
#pragma unroll
      for (int nt = 0; nt < 2; ++nt)
        acc[mt][nt] = __builtin_amdgcn_mfma_f32_16x16x32_bf16(
            a[mt], bb[nt], acc[mt][nt], 0, 0, 0);
  }
}

// ---- fused: 3x (3-tap gathered GEMM) + BN+sigmoid sum + gate by feats ----
__global__ __launch_bounds__(512, 4) void recon_kernel(
    const unsigned short* __restrict__ F16, const float* __restrict__ F32,
    const unsigned short* __restrict__ Wt,
    const int* __restrict__ nbrx, const int* __restrict__ nbry,
    const int* __restrict__ nbrz,
    const float* __restrict__ g1, const float* __restrict__ b1,
    const float* __restrict__ g2, const float* __restrict__ b2,
    const float* __restrict__ g3, const float* __restrict__ b3,
    float* __restrict__ out) {
  __shared__ unsigned short buf0[BM * 128];  // 32 KB (half-K)
  __shared__ unsigned short buf1[BM * 128];  // 32 KB
  const int tid = threadIdx.x;
  const int wid = tid >> 6, lane = tid & 63;
  const int m = lane & 15, quad = lane >> 4;
  const int wn = wid & 3, wm = wid >> 2;
  const int m0 = blockIdx.x * BM;
  const int col_base = blockIdx.y * 128 + wn * 32;
  const float RSQ = 0.9999950000374998f;  // rsqrt(1+1e-5)

  const int* nbp[3] = {nbrx, nbry, nbrz};
  const float* gp3[3] = {g1, g2, g3};
  const float* bp3[3] = {b1, b2, b3};

  accfrag_t sum[4][2], acc[4][2];
#pragma unroll
  for (int mt = 0; mt < 4; ++mt)
#pragma unroll
    for (int nt = 0; nt < 2; ++nt) {
      sum[mt][nt] = (accfrag_t){0.f, 0.f, 0.f, 0.f};
      acc[mt][nt] = (accfrag_t){0.f, 0.f, 0.f, 0.f};
    }

  int nb_cur[4], nb_nxt[4];
  load_nb(nbp[0], 0, m0, wid, lane, nb_cur);
  issue_stage(F16, buf0, 0, nb_cur, wid, lane);
  __syncthreads();  // drains prologue stage

  for (int t = 0; t < 9; ++t) {
    const int conv = (t >= 6) ? 2 : ((t >= 3) ? 1 : 0);
    const int tap = t - conv * 3;
    const unsigned short* Wtap = Wt + ((size_t)t << 16);
    if (t < 8) {
      const int t2 = t + 1;
      const int conv2 = (t2 >= 6) ? 2 : ((t2 >= 3) ? 1 : 0);
      load_nb(nbp[conv2], t2 - conv2 * 3, m0, wid, lane, nb_nxt);
    }
    issue_stage(F16, buf1, 1, nb_cur, wid, lane);     // half1 of tap t
    compute_half(buf0, Wtap, 0, wm, m, quad, col_base, acc);
    __syncthreads();  // drains buf1 writes (+ nb_nxt loads)
    if (t < 8) issue_stage(F16, buf0, 0, nb_nxt, wid, lane);  // half0 of tap t+1
    compute_half(buf1, Wtap, 1, wm, m, quad, col_base, acc);
    __syncthreads();  // drains buf0 writes
#pragma unroll
    for (int i = 0; i < 4; ++i) nb_cur[i] = nb_nxt[i];

    if (tap == 2) {  // end of conv: BN(eval) + sigmoid, accumulate, reset acc
      const float* gp = gp3[conv];
      const float* bp = bp3[conv];
#pragma unroll
      for (int nt = 0; nt < 2; ++nt) {
        int c = col_base + nt * 16 + m;
        float sc = gp[c] * RSQ;
        float bi = bp[c];
#pragma unroll
        for (int mt = 0; mt < 4; ++mt)
#pragma unroll
          for (int r = 0; r < 4; ++r) {
            float y = acc[mt][nt][r];
            sum[mt][nt][r] += 1.0f / (1.0f + __expf(-(y * sc + bi)));
            acc[mt][nt][r] = 0.f;
          }
      }
    }
  }

  // final gate: out = sum * feats (fp32)
#pragma unroll
  for (int mt = 0; mt < 4; ++mt)
#pragma unroll
    for (int r = 0; r < 4; ++r) {
      int row = m0 + wm * 64 + mt * 16 + quad * 4 + r;
      if (row < NVOX) {
#pragma unroll
        for (int nt = 0; nt < 2; ++nt) {
          int c = col_base + nt * 16 + m;
          size_t off = ((size_t)row << 8) + c;
          out[off] = sum[mt][nt][r] * F32[off];
        }
      }
    }
}

extern "C" void kernel_launch(void* const* d_in, const int* in_sizes, int n_in,
                              void* d_out, int out_size, void* d_ws, size_t ws_size,
                              hipStream_t stream) {
  const float* feats = (const float*)d_in[0];
  const float* w1 = (const float*)d_in[1];
  const float* w2 = (const float*)d_in[2];
  const float* w3 = (const float*)d_in[3];
  const float* g1 = (const float*)d_in[4];
  const float* b1 = (const float*)d_in[5];
  const float* g2 = (const float*)d_in[6];
  const float* b2 = (const float*)d_in[7];
  const float* g3 = (const float*)d_in[8];
  const float* b3 = (const float*)d_in[9];
  const int* nbrx = (const int*)d_in[10];
  const int* nbry = (const int*)d_in[11];
  const int* nbrz = (const int*)d_in[12];
  float* out = (float*)d_out;

  // ws layout: F16 (NPAD*256 bf16 = 76.8 MB) | Wt (9*65536 bf16 = 1.18 MB)
  unsigned short* F16 = (unsigned short*)d_ws;
  unsigned short* Wt = F16 + (size_t)NPAD * CCH;

  cvt_feats_kernel<<<NPAD * CCH / 8 / 256, 256, 0, stream>>>(feats, F16);
  dim3 wgrid(8, 8, 9);
  cvt_w_kernel<<<wgrid, 256, 0, stream>>>(w1, w2, w3, Wt);
  dim3 grid(NPAD / BM, 2);
  recon_kernel<<<grid, 512, 0, stream>>>(F16, feats, Wt, nbrx, nbry, nbrz,
                                         g1, b1, g2, b2, g3, b3, out);
}